// Round 3
// baseline (392.359 us; speedup 1.0000x reference)
//
#include <hip/hip_runtime.h>

#define E_TOT 100000

typedef _Float16 half8   __attribute__((ext_vector_type(8)));
typedef float    float4v __attribute__((ext_vector_type(4)));

__device__ __forceinline__ float silu_f(float x) {
    return x / (1.0f + __expf(-x));
}

// ---- prep kernel: fp32 weights -> fp16 "B-fragment-linear" layout in ws ----
// Fragment for lane L of a wave, tile (nt,kt): B[k = kt*32 + (L>>4)*8 + j][n = nt*16 + (L&15)], j=0..7
// stored contiguously at [ ... ][lane][j] so a wave's half8 loads are 1 KB coalesced.
//   W0f: [nt=8][kt=2][64][8]  -> halves     0 ..  8191   (W0 is 64x128)
//   W1f: [nt=8][kt=4][64][8]  -> halves  8192 .. 24575   (W1 is 128x128)
//   Pf : [m=5][nt=4][kt=4][64][8] ->    24576 .. 65535   (P is 128x64)
__global__ void prep_weights(const float* __restrict__ W0,
                             const float* __restrict__ W1,
                             const float* __restrict__ P1,
                             const float* __restrict__ P2,
                             const float* __restrict__ P3,
                             const float* __restrict__ P4,
                             const float* __restrict__ P5,
                             _Float16* __restrict__ wf)
{
    int gid  = blockIdx.x * 256 + threadIdx.x;   // 65536 total
    int j    = gid & 7;
    int lane = (gid >> 3) & 63;
    int krow = ((lane >> 4) << 3) + j;           // k offset within 32-block
    int ncol = lane & 15;
    float v;
    if (gid < 8192) {
        int kt = (gid >> 9) & 1, nt = gid >> 10;
        v = W0[(kt * 32 + krow) * 128 + nt * 16 + ncol];
    } else if (gid < 24576) {
        int rem = gid - 8192;
        int kt = (rem >> 9) & 3, nt = rem >> 11;
        v = W1[(kt * 32 + krow) * 128 + nt * 16 + ncol];
    } else {
        int rem = gid - 24576;
        int kt = (rem >> 9) & 3, nt = (rem >> 11) & 3, m = rem >> 13;
        const float* Pm = (m == 0) ? P1 : (m == 1) ? P2 : (m == 2) ? P3 : (m == 3) ? P4 : P5;
        v = Pm[(kt * 32 + krow) * 64 + nt * 16 + ncol];
    }
    wf[gid] = (_Float16)v;
}

// ---- main kernel: 1 wave / block, 16 rows, 4.3 KB LDS, 6250 blocks ----
// G3 fused with epilogue per n-tile keeps live acc at 5xf32x4 = 20 regs;
// fine-grained grid gives ~24 waves/CU available (vs 12 at 32 rows/wave).
__global__ __launch_bounds__(64, 4)
void tpmlp_main(const float* __restrict__ emb,
                const float* __restrict__ x1,
                const float* __restrict__ x2,
                const _Float16* __restrict__ wf,
                float* __restrict__ out)
{
    const float INV_SQRT_EMB = 0.125f;
    const float INV_SQRT_H   = 0.08838834764831845f;
    const float INV_SQRT3    = 0.5773502691896258f;
    const float INV_SQRT6    = 0.4082482904638631f;
    const float INV_SQRT2_C  = 0.7071067811865476f;

    __shared__ _Float16 s_h[16 * 136];   // h buffer, reused h0 -> h1 (4352 B)

    const int lane = threadIdx.x;        // 0..63
    const int l15  = lane & 15;
    const int lq   = lane >> 4;
    const int e0   = blockIdx.x * 16;    // 6250 * 16 == 100000 exactly, no guards

    const _Float16* __restrict__ W0f = wf;
    const _Float16* __restrict__ W1f = wf + 8192;
    const _Float16* __restrict__ Pf  = wf + 24576;

    // ---- x2 prefetch for this lane's 4 epilogue rows (overlaps whole MLP) ----
    float4v x2pre[4];
    #pragma unroll
    for (int r = 0; r < 4; ++r)
        x2pre[r] = *(const float4v*)(x2 + (size_t)(e0 + lq * 4 + r) * 4);

    // ---- A1 fragments straight from emb (fp32 global -> fp16 regs) ----
    half8 a0, a1;
    {
        const float* er = emb + (size_t)(e0 + l15) * 64 + lq * 8;
        float4v v0 = *(const float4v*)er;
        float4v v1 = *(const float4v*)(er + 4);
        float4v v2 = *(const float4v*)(er + 32);
        float4v v3 = *(const float4v*)(er + 36);
        #pragma unroll
        for (int q = 0; q < 4; ++q) {
            a0[q] = (_Float16)v0[q]; a0[4 + q] = (_Float16)v1[q];
            a1[q] = (_Float16)v2[q]; a1[4 + q] = (_Float16)v3[q];
        }
    }

    // ---- G1: h0 = silu(emb @ W0 / 8) ----
    #pragma unroll
    for (int nt = 0; nt < 8; ++nt) {
        half8 b0 = *(const half8*)&W0f[((nt * 2 + 0) * 64 + lane) * 8];
        half8 b1 = *(const half8*)&W0f[((nt * 2 + 1) * 64 + lane) * 8];
        float4v c = {0.f, 0.f, 0.f, 0.f};
        c = __builtin_amdgcn_mfma_f32_16x16x32_f16(a0, b0, c, 0, 0, 0);
        c = __builtin_amdgcn_mfma_f32_16x16x32_f16(a1, b1, c, 0, 0, 0);
        #pragma unroll
        for (int r = 0; r < 4; ++r)
            s_h[(lq * 4 + r) * 136 + nt * 16 + l15] =
                (_Float16)silu_f(c[r] * INV_SQRT_EMB);
    }
    __syncthreads();   // single-wave block: effectively free

    // ---- A2 fragments from h0 ----
    half8 a2[4];
    #pragma unroll
    for (int kt = 0; kt < 4; ++kt)
        a2[kt] = *(const half8*)&s_h[l15 * 136 + kt * 32 + lq * 8];
    __syncthreads();

    // ---- G2: h1 = silu(h0 @ W1 / sqrt(128)) ----
    #pragma unroll
    for (int nt = 0; nt < 8; ++nt) {
        float4v c = {0.f, 0.f, 0.f, 0.f};
        #pragma unroll
        for (int kt = 0; kt < 4; ++kt) {
            half8 b = *(const half8*)&W1f[((nt * 4 + kt) * 64 + lane) * 8];
            c = __builtin_amdgcn_mfma_f32_16x16x32_f16(a2[kt], b, c, 0, 0, 0);
        }
        #pragma unroll
        for (int r = 0; r < 4; ++r)
            s_h[(lq * 4 + r) * 136 + nt * 16 + l15] =
                (_Float16)silu_f(c[r] * INV_SQRT_H);
    }
    __syncthreads();

    // ---- A3 fragments from h1 (no further LDS writes) ----
    half8 a3[4];
    #pragma unroll
    for (int kt = 0; kt < 4; ++kt)
        a3[kt] = *(const half8*)&s_h[l15 * 136 + kt * 32 + lq * 8];

    // ---- G3 fused with epilogue, one n-tile at a time (acc = 20 regs live) ----
    #pragma unroll
    for (int nt = 0; nt < 4; ++nt) {
        float4v acc[5];
        #pragma unroll
        for (int m = 0; m < 5; ++m)
            acc[m] = (float4v){0.f, 0.f, 0.f, 0.f};

        #pragma unroll
        for (int m = 0; m < 5; ++m)
            #pragma unroll
            for (int kt = 0; kt < 4; ++kt) {
                half8 b = *(const half8*)&Pf[((m * 16 + nt * 4 + kt) * 64 + lane) * 8];
                acc[m] = __builtin_amdgcn_mfma_f32_16x16x32_f16(a3[kt], b, acc[m], 0, 0, 0);
            }

        // ---- Epilogue for this n-tile: C-frag layout row = lq*4 + r, col = l15 ----
        const int u = nt * 16 + l15;
        #pragma unroll
        for (int r = 0; r < 4; ++r) {
            const int e = e0 + lq * 4 + r;
            const float* x1p = x1 + (size_t)e * 256;
            float x20 = x2pre[r][0], b0 = x2pre[r][1], b1 = x2pre[r][2], b2 = x2pre[r][3];
            float* op = out + (size_t)e * 448;

            float w1 = acc[0][r] * INV_SQRT_H;
            float w2 = acc[1][r] * INV_SQRT_H;
            float w3 = acc[2][r] * INV_SQRT_H;
            float w4 = acc[3][r] * INV_SQRT_H;
            float w5 = acc[4][r] * INV_SQRT_H;

            float x10 = x1p[u];
            float a_0 = x1p[64 + 3 * u];
            float a_1 = x1p[65 + 3 * u];
            float a_2 = x1p[66 + 3 * u];

            float dot = a_0 * b0 + a_1 * b1 + a_2 * b2;

            op[u] = INV_SQRT2_C * (w1 * x10 * x20 + w4 * dot * INV_SQRT3);

            op[64 + 3 * u] = INV_SQRT2_C * (w2 * a_0 * x20 + w3 * x10 * b0);
            op[65 + 3 * u] = INV_SQRT2_C * (w2 * a_1 * x20 + w3 * x10 * b1);
            op[66 + 3 * u] = INV_SQRT2_C * (w2 * a_2 * x20 + w3 * x10 * b2);

            op[256 + 3 * u] = w5 * (a_1 * b2 - a_2 * b1) * INV_SQRT6;
            op[257 + 3 * u] = w5 * (a_2 * b0 - a_0 * b2) * INV_SQRT6;
            op[258 + 3 * u] = w5 * (a_0 * b1 - a_1 * b0) * INV_SQRT6;
        }
    }
}

extern "C" void kernel_launch(void* const* d_in, const int* in_sizes, int n_in,
                              void* d_out, int out_size, void* d_ws, size_t ws_size,
                              hipStream_t stream) {
    const float* emb = (const float*)d_in[0];
    const float* x1  = (const float*)d_in[1];
    const float* x2  = (const float*)d_in[2];
    const float* W0  = (const float*)d_in[3];
    const float* W1  = (const float*)d_in[4];
    const float* P1  = (const float*)d_in[5];
    const float* P2  = (const float*)d_in[6];
    const float* P3  = (const float*)d_in[7];
    const float* P4  = (const float*)d_in[8];
    const float* P5  = (const float*)d_in[9];

    _Float16* wf = (_Float16*)d_ws;   // needs 131072 bytes

    prep_weights<<<dim3(256), dim3(256), 0, stream>>>(W0, W1, P1, P2, P3, P4, P5, wf);
    tpmlp_main<<<dim3((E_TOT + 15) / 16), dim3(64), 0, stream>>>(
        emb, x1, x2, wf, (float*)d_out);
}

// Round 4
// 372.523 us; speedup vs baseline: 1.0532x; 1.0532x over previous
//
#include <hip/hip_runtime.h>

#define E_TOT 100000

typedef _Float16 half8   __attribute__((ext_vector_type(8)));
typedef float    float4v __attribute__((ext_vector_type(4)));

__device__ __forceinline__ float silu_f(float x) {
    return x / (1.0f + __expf(-x));
}

// ---- prep kernel: fp32 weights -> fp16 "B-fragment-linear" layout in ws ----
// Fragment for lane L of a wave, tile (nt,kt): B[k = kt*32 + (L>>4)*8 + j][n = nt*16 + (L&15)], j=0..7
// stored contiguously at [ ... ][lane][j] so a wave's half8 loads are 1 KB coalesced.
//   W0f: [nt=8][kt=2][64][8]  -> halves     0 ..  8191   (W0 is 64x128)
//   W1f: [nt=8][kt=4][64][8]  -> halves  8192 .. 24575   (W1 is 128x128)
//   Pf : [m=5][nt=4][kt=4][64][8] ->    24576 .. 65535   (P is 128x64)
__global__ void prep_weights(const float* __restrict__ W0,
                             const float* __restrict__ W1,
                             const float* __restrict__ P1,
                             const float* __restrict__ P2,
                             const float* __restrict__ P3,
                             const float* __restrict__ P4,
                             const float* __restrict__ P5,
                             _Float16* __restrict__ wf)
{
    int gid  = blockIdx.x * 256 + threadIdx.x;   // 65536 total
    int j    = gid & 7;
    int lane = (gid >> 3) & 63;
    int krow = ((lane >> 4) << 3) + j;           // k offset within 32-block
    int ncol = lane & 15;
    float v;
    if (gid < 8192) {
        int kt = (gid >> 9) & 1, nt = gid >> 10;
        v = W0[(kt * 32 + krow) * 128 + nt * 16 + ncol];
    } else if (gid < 24576) {
        int rem = gid - 8192;
        int kt = (rem >> 9) & 3, nt = rem >> 11;
        v = W1[(kt * 32 + krow) * 128 + nt * 16 + ncol];
    } else {
        int rem = gid - 24576;
        int kt = (rem >> 9) & 3, nt = (rem >> 11) & 3, m = rem >> 13;
        const float* Pm = (m == 0) ? P1 : (m == 1) ? P2 : (m == 2) ? P3 : (m == 3) ? P4 : P5;
        v = Pm[(kt * 32 + krow) * 64 + nt * 16 + ncol];
    }
    wf[gid] = (_Float16)v;
}

// ---- main kernel: 4 waves x 32 rows = 128 rows/block, 34.8 KB LDS, 782 blocks ----
// Barrier-lockstep waves share the 128 KB weight stream through L1 (round-0's win);
// 2 M-tiles/wave amortize every B-fragment load; G3 fused with epilogue per n-tile
// keeps live acc at 2x5xf32x4 = 40 regs -> fits 4 waves/SIMD.
__global__ __launch_bounds__(256, 4)
void tpmlp_main(const float* __restrict__ emb,
                const float* __restrict__ x1,
                const float* __restrict__ x2,
                const _Float16* __restrict__ wf,
                float* __restrict__ out)
{
    const float INV_SQRT_EMB = 0.125f;
    const float INV_SQRT_H   = 0.08838834764831845f;
    const float INV_SQRT3    = 0.5773502691896258f;
    const float INV_SQRT6    = 0.4082482904638631f;
    const float INV_SQRT2_C  = 0.7071067811865476f;

    __shared__ _Float16 s_h[128 * 136];   // per-wave 32-row h buffer, reused h0 -> h1

    const int tid  = threadIdx.x;
    const int lane = tid & 63;
    const int wv   = tid >> 6;
    const int l15  = lane & 15;
    const int lq   = lane >> 4;
    const int r0   = blockIdx.x * 128 + wv * 32;   // wave's first row
    const int hb   = wv * 32;                      // wave's LDS row base

    const _Float16* __restrict__ W0f = wf;
    const _Float16* __restrict__ W1f = wf + 8192;
    const _Float16* __restrict__ Pf  = wf + 24576;

    // ---- A1 fragments straight from emb (fp32 global -> fp16 regs), both tiles ----
    half8 a0[2], a1[2];
    #pragma unroll
    for (int t = 0; t < 2; ++t) {
        int row = r0 + t * 16 + l15;
        if (row >= E_TOT) row = E_TOT - 1;         // clamp (last block only)
        const float* er = emb + (size_t)row * 64 + lq * 8;
        float4v v0 = *(const float4v*)er;
        float4v v1 = *(const float4v*)(er + 4);
        float4v v2 = *(const float4v*)(er + 32);
        float4v v3 = *(const float4v*)(er + 36);
        #pragma unroll
        for (int q = 0; q < 4; ++q) {
            a0[t][q] = (_Float16)v0[q]; a0[t][4 + q] = (_Float16)v1[q];
            a1[t][q] = (_Float16)v2[q]; a1[t][4 + q] = (_Float16)v3[q];
        }
    }

    // ---- G1: h0 = silu(emb @ W0 / 8) ---- (each B-fragment feeds both tiles)
    #pragma unroll
    for (int nt = 0; nt < 8; ++nt) {
        half8 b0 = *(const half8*)&W0f[((nt * 2 + 0) * 64 + lane) * 8];
        half8 b1 = *(const half8*)&W0f[((nt * 2 + 1) * 64 + lane) * 8];
        #pragma unroll
        for (int t = 0; t < 2; ++t) {
            float4v c = {0.f, 0.f, 0.f, 0.f};
            c = __builtin_amdgcn_mfma_f32_16x16x32_f16(a0[t], b0, c, 0, 0, 0);
            c = __builtin_amdgcn_mfma_f32_16x16x32_f16(a1[t], b1, c, 0, 0, 0);
            #pragma unroll
            for (int r = 0; r < 4; ++r)
                s_h[(hb + t * 16 + lq * 4 + r) * 136 + nt * 16 + l15] =
                    (_Float16)silu_f(c[r] * INV_SQRT_EMB);
        }
    }
    __syncthreads();

    // ---- A2 fragments from h0 ----
    half8 a2[2][4];
    #pragma unroll
    for (int t = 0; t < 2; ++t)
        #pragma unroll
        for (int kt = 0; kt < 4; ++kt)
            a2[t][kt] = *(const half8*)&s_h[(hb + t * 16 + l15) * 136 + kt * 32 + lq * 8];
    __syncthreads();   // all reads done before h1 overwrites

    // ---- G2: h1 = silu(h0 @ W1 / sqrt(128)) ----
    #pragma unroll
    for (int nt = 0; nt < 8; ++nt) {
        half8 b[4];
        #pragma unroll
        for (int kt = 0; kt < 4; ++kt)
            b[kt] = *(const half8*)&W1f[((nt * 4 + kt) * 64 + lane) * 8];
        #pragma unroll
        for (int t = 0; t < 2; ++t) {
            float4v c = {0.f, 0.f, 0.f, 0.f};
            #pragma unroll
            for (int kt = 0; kt < 4; ++kt)
                c = __builtin_amdgcn_mfma_f32_16x16x32_f16(a2[t][kt], b[kt], c, 0, 0, 0);
            #pragma unroll
            for (int r = 0; r < 4; ++r)
                s_h[(hb + t * 16 + lq * 4 + r) * 136 + nt * 16 + l15] =
                    (_Float16)silu_f(c[r] * INV_SQRT_H);
        }
    }
    __syncthreads();

    // ---- A3 fragments from h1 (no further LDS writes) ----
    half8 a3[2][4];
    #pragma unroll
    for (int t = 0; t < 2; ++t)
        #pragma unroll
        for (int kt = 0; kt < 4; ++kt)
            a3[t][kt] = *(const half8*)&s_h[(hb + t * 16 + l15) * 136 + kt * 32 + lq * 8];

    // ---- G3 fused with epilogue, one n-tile at a time (acc = 40 regs live) ----
    #pragma unroll
    for (int nt = 0; nt < 4; ++nt) {
        float4v acc[2][5];
        #pragma unroll
        for (int t = 0; t < 2; ++t)
            #pragma unroll
            for (int m = 0; m < 5; ++m)
                acc[t][m] = (float4v){0.f, 0.f, 0.f, 0.f};

        #pragma unroll
        for (int m = 0; m < 5; ++m)
            #pragma unroll
            for (int kt = 0; kt < 4; ++kt) {
                half8 b = *(const half8*)&Pf[((m * 16 + nt * 4 + kt) * 64 + lane) * 8];
                #pragma unroll
                for (int t = 0; t < 2; ++t)
                    acc[t][m] = __builtin_amdgcn_mfma_f32_16x16x32_f16(a3[t][kt], b, acc[t][m], 0, 0, 0);
            }

        // ---- Epilogue for this n-tile: C-frag layout row = t*16 + lq*4 + r, col = l15 ----
        const int u = nt * 16 + l15;
        #pragma unroll
        for (int t = 0; t < 2; ++t)
            #pragma unroll
            for (int r = 0; r < 4; ++r) {
                const int e = r0 + t * 16 + lq * 4 + r;
                if (e < E_TOT) {
                    const float* x1p = x1 + (size_t)e * 256;
                    float4v x2v = *(const float4v*)(x2 + (size_t)e * 4);
                    float x20 = x2v[0], b0 = x2v[1], b1 = x2v[2], b2 = x2v[3];
                    float* op = out + (size_t)e * 448;

                    float w1 = acc[t][0][r] * INV_SQRT_H;
                    float w2 = acc[t][1][r] * INV_SQRT_H;
                    float w3 = acc[t][2][r] * INV_SQRT_H;
                    float w4 = acc[t][3][r] * INV_SQRT_H;
                    float w5 = acc[t][4][r] * INV_SQRT_H;

                    float x10 = x1p[u];
                    float a_0 = x1p[64 + 3 * u];
                    float a_1 = x1p[65 + 3 * u];
                    float a_2 = x1p[66 + 3 * u];

                    float dot = a_0 * b0 + a_1 * b1 + a_2 * b2;

                    op[u] = INV_SQRT2_C * (w1 * x10 * x20 + w4 * dot * INV_SQRT3);

                    op[64 + 3 * u] = INV_SQRT2_C * (w2 * a_0 * x20 + w3 * x10 * b0);
                    op[65 + 3 * u] = INV_SQRT2_C * (w2 * a_1 * x20 + w3 * x10 * b1);
                    op[66 + 3 * u] = INV_SQRT2_C * (w2 * a_2 * x20 + w3 * x10 * b2);

                    op[256 + 3 * u] = w5 * (a_1 * b2 - a_2 * b1) * INV_SQRT6;
                    op[257 + 3 * u] = w5 * (a_2 * b0 - a_0 * b2) * INV_SQRT6;
                    op[258 + 3 * u] = w5 * (a_0 * b1 - a_1 * b0) * INV_SQRT6;
                }
            }
    }
}

extern "C" void kernel_launch(void* const* d_in, const int* in_sizes, int n_in,
                              void* d_out, int out_size, void* d_ws, size_t ws_size,
                              hipStream_t stream) {
    const float* emb = (const float*)d_in[0];
    const float* x1  = (const float*)d_in[1];
    const float* x2  = (const float*)d_in[2];
    const float* W0  = (const float*)d_in[3];
    const float* W1  = (const float*)d_in[4];
    const float* P1  = (const float*)d_in[5];
    const float* P2  = (const float*)d_in[6];
    const float* P3  = (const float*)d_in[7];
    const float* P4  = (const float*)d_in[8];
    const float* P5  = (const float*)d_in[9];

    _Float16* wf = (_Float16*)d_ws;   // needs 131072 bytes

    prep_weights<<<dim3(256), dim3(256), 0, stream>>>(W0, W1, P1, P2, P3, P4, P5, wf);
    tpmlp_main<<<dim3((E_TOT + 127) / 128), dim3(256), 0, stream>>>(
        emb, x1, x2, wf, (float*)d_out);
}

// Round 6
// 365.914 us; speedup vs baseline: 1.0723x; 1.0181x over previous
//
#include <hip/hip_runtime.h>

#define E_TOT 100000

typedef _Float16 half8   __attribute__((ext_vector_type(8)));
typedef float    float4v __attribute__((ext_vector_type(4)));

__device__ __forceinline__ float silu_f(float x) {
    return x / (1.0f + __expf(-x));
}

// ---- prep kernel: fp32 weights -> fp16 "B-fragment-linear" layout in ws ----
// Fragment for lane L, tile (nt,kt): B[k = kt*32 + (L>>4)*8 + j][n = nt*16 + (L&15)], j=0..7
//   W0f: [nt=8][kt=2][64][8]  -> halves     0 ..  8191   (W0 is 64x128)   * 0.125 folded
//   W1f: [nt=8][kt=4][64][8]  -> halves  8192 .. 24575   (W1 is 128x128)  * 1/sqrt(128) folded
//   Pf : [m=5][nt=4][kt=4][64][8] ->    24576 .. 65535   (P is 128x64)    * 1/sqrt(128) folded
__global__ void prep_weights(const float* __restrict__ W0,
                             const float* __restrict__ W1,
                             const float* __restrict__ P1,
                             const float* __restrict__ P2,
                             const float* __restrict__ P3,
                             const float* __restrict__ P4,
                             const float* __restrict__ P5,
                             _Float16* __restrict__ wf)
{
    const float INV_SQRT_H = 0.08838834764831845f;
    int gid  = blockIdx.x * 256 + threadIdx.x;   // 65536 total
    int j    = gid & 7;
    int lane = (gid >> 3) & 63;
    int krow = ((lane >> 4) << 3) + j;           // k offset within 32-block
    int ncol = lane & 15;
    float v;
    if (gid < 8192) {
        int kt = (gid >> 9) & 1, nt = gid >> 10;
        v = W0[(kt * 32 + krow) * 128 + nt * 16 + ncol] * 0.125f;   // exact (2^-3)
    } else if (gid < 24576) {
        int rem = gid - 8192;
        int kt = (rem >> 9) & 3, nt = rem >> 11;
        v = W1[(kt * 32 + krow) * 128 + nt * 16 + ncol] * INV_SQRT_H;
    } else {
        int rem = gid - 24576;
        int kt = (rem >> 9) & 3, nt = (rem >> 11) & 3, m = rem >> 13;
        const float* Pm = (m == 0) ? P1 : (m == 1) ? P2 : (m == 2) ? P3 : (m == 3) ? P4 : P5;
        v = Pm[(kt * 32 + krow) * 64 + nt * 16 + ncol] * INV_SQRT_H;
    }
    wf[gid] = (_Float16)v;
}

// ---- main kernel: 4 waves x 16 rows = 64 rows/block (R0 geometry), 1563 blocks ----
// G3 computes the TRANSPOSED product by swapping MFMA operands:
//   mfma(Pf_frag, a3_frag) -> D[row = u_local][col = e_local]
// so each lane owns ONE output row e (= e0+wv*16+l15) and 4 consecutive u's
// (= nt*16 + lq*4 + r). All x1 reads / out writes are aligned float4s with
// compile-time /3 %3; w stays in registers (no LDS staging, no fences).
__global__ __launch_bounds__(256, 4)
void tpmlp_main(const float* __restrict__ emb,
                const float* __restrict__ x1,
                const float* __restrict__ x2,
                const _Float16* __restrict__ wf,
                float* __restrict__ out)
{
    const float INV_SQRT3   = 0.5773502691896258f;
    const float INV_SQRT6   = 0.4082482904638631f;
    const float INV_SQRT2_C = 0.7071067811865476f;

    __shared__ _Float16 s_h[64 * 136];   // h buffer, reused h0 -> h1 (17408 B)

    const int tid  = threadIdx.x;
    const int lane = tid & 63;
    const int wv   = tid >> 6;
    const int l15  = lane & 15;
    const int lq   = lane >> 4;
    const int e0   = blockIdx.x * 64;

    const int erow  = e0 + wv * 16 + l15;          // this lane's output row
    const bool valid = erow < E_TOT;
    const int crow  = valid ? erow : (E_TOT - 1);  // clamped for loads

    const _Float16* __restrict__ W0f = wf;
    const _Float16* __restrict__ W1f = wf + 8192;
    const _Float16* __restrict__ Pf  = wf + 24576;

    // x2 for this lane's single row (prefetch; overlaps the whole MLP)
    const float4v x2v = *(const float4v*)(x2 + (size_t)crow * 4);

    // ---- A1 fragments straight from emb (fp32 global -> fp16 regs) ----
    half8 a0, a1;
    {
        const float* er = emb + (size_t)crow * 64 + lq * 8;
        float4v v0 = *(const float4v*)er;
        float4v v1 = *(const float4v*)(er + 4);
        float4v v2 = *(const float4v*)(er + 32);
        float4v v3 = *(const float4v*)(er + 36);
        #pragma unroll
        for (int q = 0; q < 4; ++q) {
            a0[q] = (_Float16)v0[q]; a0[4 + q] = (_Float16)v1[q];
            a1[q] = (_Float16)v2[q]; a1[4 + q] = (_Float16)v3[q];
        }
    }

    // ---- G1: h0 = silu(emb @ W0f)  (scale pre-folded into W0f) ----
    #pragma unroll
    for (int nt = 0; nt < 8; ++nt) {
        half8 b0 = *(const half8*)&W0f[((nt * 2 + 0) * 64 + lane) * 8];
        half8 b1 = *(const half8*)&W0f[((nt * 2 + 1) * 64 + lane) * 8];
        float4v c = {0.f, 0.f, 0.f, 0.f};
        c = __builtin_amdgcn_mfma_f32_16x16x32_f16(a0, b0, c, 0, 0, 0);
        c = __builtin_amdgcn_mfma_f32_16x16x32_f16(a1, b1, c, 0, 0, 0);
        #pragma unroll
        for (int r = 0; r < 4; ++r)
            s_h[(wv * 16 + lq * 4 + r) * 136 + nt * 16 + l15] =
                (_Float16)silu_f(c[r]);
    }
    __syncthreads();

    // ---- A2 fragments from h0 ----
    half8 a2[4];
    #pragma unroll
    for (int kt = 0; kt < 4; ++kt)
        a2[kt] = *(const half8*)&s_h[(wv * 16 + l15) * 136 + kt * 32 + lq * 8];
    __syncthreads();   // all reads done before h1 overwrites

    // ---- G2: h1 = silu(h0 @ W1f)  (scale pre-folded into W1f) ----
    #pragma unroll
    for (int nt = 0; nt < 8; ++nt) {
        float4v c = {0.f, 0.f, 0.f, 0.f};
        #pragma unroll
        for (int kt = 0; kt < 4; ++kt) {
            half8 b = *(const half8*)&W1f[((nt * 4 + kt) * 64 + lane) * 8];
            c = __builtin_amdgcn_mfma_f32_16x16x32_f16(a2[kt], b, c, 0, 0, 0);
        }
        #pragma unroll
        for (int r = 0; r < 4; ++r)
            s_h[(wv * 16 + lq * 4 + r) * 136 + nt * 16 + l15] =
                (_Float16)silu_f(c[r]);
    }
    __syncthreads();

    // ---- A3 fragments from h1 (no further LDS writes) ----
    half8 a3[4];
    #pragma unroll
    for (int kt = 0; kt < 4; ++kt)
        a3[kt] = *(const half8*)&s_h[(wv * 16 + l15) * 136 + kt * 32 + lq * 8];

    const float* x1r = x1 + (size_t)crow * 256;
    float*       op  = out + (size_t)crow * 448;
    const float x20 = x2v[0];
    const float bi0 = x2v[1], bi1 = x2v[2], bi2 = x2v[3];

    // ---- G3 (operand-swapped) + fully-vectorized epilogue, per n-tile ----
    #pragma unroll
    for (int nt = 0; nt < 4; ++nt) {
        // x1 for this lane's (row, u-group): u = nt*16 + lq*4 + t, all aligned float4
        float4v x10v = *(const float4v*)(x1r + nt * 16 + 4 * lq);
        float4v av0  = *(const float4v*)(x1r + 64 + nt * 48 + 12 * lq);
        float4v av1  = *(const float4v*)(x1r + 64 + nt * 48 + 12 * lq + 4);
        float4v av2  = *(const float4v*)(x1r + 64 + nt * 48 + 12 * lq + 8);

        // w_m^T fragments: mfma(P-frag as A, h1-frag as B) -> D[u_local][e_local]
        float4v acc[5];
        #pragma unroll
        for (int m = 0; m < 5; ++m)
            acc[m] = (float4v){0.f, 0.f, 0.f, 0.f};
        #pragma unroll
        for (int m = 0; m < 5; ++m)
            #pragma unroll
            for (int kt = 0; kt < 4; ++kt) {
                half8 p = *(const half8*)&Pf[((m * 16 + nt * 4 + kt) * 64 + lane) * 8];
                acc[m] = __builtin_amdgcn_mfma_f32_16x16x32_f16(p, a3[kt], acc[m], 0, 0, 0);
            }
        // lane now holds w_m[e = crow][u = nt*16 + lq*4 + t] = acc[m][t] (scale folded)

        float af[12];
        #pragma unroll
        for (int q = 0; q < 4; ++q) {
            af[q] = av0[q]; af[4 + q] = av1[q]; af[8 + q] = av2[q];
        }

        // out_0e: one float4
        float4v o0;
        #pragma unroll
        for (int t = 0; t < 4; ++t) {
            float dt = af[3 * t] * bi0 + af[3 * t + 1] * bi1 + af[3 * t + 2] * bi2;
            o0[t] = INV_SQRT2_C * (acc[0][t] * x10v[t] * x20 + acc[3][t] * dt * INV_SQRT3);
        }
        if (valid)
            *(float4v*)(op + nt * 16 + 4 * lq) = o0;

        // out_1o and out_1e: 12 consecutive floats each = 3 float4s each
        #pragma unroll
        for (int q = 0; q < 3; ++q) {
            float4v oo, oe;
            #pragma unroll
            for (int z = 0; z < 4; ++z) {
                const int e2 = q * 4 + z;         // 0..11, compile-time
                const int t  = e2 / 3;            // compile-time
                const int i  = e2 - 3 * t;        // compile-time
                const float bii = (i == 0) ? bi0 : (i == 1) ? bi1 : bi2;
                oo[z] = INV_SQRT2_C * (acc[1][t] * af[e2] * x20 +
                                       acc[2][t] * x10v[t] * bii);
                float cr = (i == 0) ? af[3 * t + 1] * bi2 - af[3 * t + 2] * bi1
                         : (i == 1) ? af[3 * t + 2] * bi0 - af[3 * t + 0] * bi2
                                    : af[3 * t + 0] * bi1 - af[3 * t + 1] * bi0;
                oe[z] = acc[4][t] * cr * INV_SQRT6;
            }
            if (valid) {
                *(float4v*)(op + 64  + nt * 48 + 12 * lq + 4 * q) = oo;
                *(float4v*)(op + 256 + nt * 48 + 12 * lq + 4 * q) = oe;
            }
        }
    }
}

extern "C" void kernel_launch(void* const* d_in, const int* in_sizes, int n_in,
                              void* d_out, int out_size, void* d_ws, size_t ws_size,
                              hipStream_t stream) {
    const float* emb = (const float*)d_in[0];
    const float* x1  = (const float*)d_in[1];
    const float* x2  = (const float*)d_in[2];
    const float* W0  = (const float*)d_in[3];
    const float* W1  = (const float*)d_in[4];
    const float* P1  = (const float*)d_in[5];
    const float* P2  = (const float*)d_in[6];
    const float* P3  = (const float*)d_in[7];
    const float* P4  = (const float*)d_in[8];
    const float* P5  = (const float*)d_in[9];

    _Float16* wf = (_Float16*)d_ws;   // needs 131072 bytes

    prep_weights<<<dim3(256), dim3(256), 0, stream>>>(W0, W1, P1, P2, P3, P4, P5, wf);
    tpmlp_main<<<dim3((E_TOT + 63) / 64), dim3(256), 0, stream>>>(
        emb, x1, x2, wf, (float*)d_out);
}